// Round 10
// baseline (505.074 us; speedup 1.0000x reference)
//
#include <hip/hip_runtime.h>
#include <cstdint>
#include <cstddef>

#define TT 1000
#define NB 64000  // B*T

// ---------------------------------------------------------------------------
// NUMERICS CONTRACT (r1/r5/r6/r8/r9 verified absmax 0.0): each z[n,o] is ONE
// ascending-k fp32 fmaf chain. Do not reorder, split, or tree-reduce.
// ---------------------------------------------------------------------------

// async global->LDS DMA: 16B/lane; LDS dest = wave-uniform base + lane*16;
// global src is PER-LANE (pass base + lane*16B).
__device__ __forceinline__ void dma16(const void* g, void* l) {
  __builtin_amdgcn_global_load_lds(
      (const __attribute__((address_space(1))) unsigned int*)g,
      (__attribute__((address_space(3))) unsigned int*)l, 16, 0, 0);
}

// ---------------------------------------------------------------------------
// Global images (DMA-ready, 1KB/4KB contiguous chunks):
//   A: u32 idx = (n>>6)*KT*256 + kt*256 + kd*64 + (n&63); byte = k&3,
//      kd = (k>>2)&3  (so LDS tile is [kd][4k-dword per row] = b128-readable)
//   W: f32 idx = ot*KT*1024 + kt*1024 + (k&15)*64 + (o&63)
// ---------------------------------------------------------------------------

// ---------------------------------------------------------------------------
// gemm_wp: WAVE-PRIVATE tiles, ZERO barriers. Each wave: 64n x 64o tile,
// own LDS slice (B 2x4KB + A 2x1KB = 10KB), own global_load_lds staging,
// double-buffered. No __syncthreads anywhere: same-wave DMA->ds_read
// ordering is compiler-enforced; independent waves (16/CU) hide the waits.
// Per lane: 8n x 8o, ascending-k fmaf chain (contract).
// ---------------------------------------------------------------------------
__global__ __launch_bounds__(256) void gemm_wp(
    const unsigned int* __restrict__ Aswz, const float* __restrict__ Wswz,
    float* __restrict__ Z, int KT, int otmask, int otshift, int Zld,
    int Ostore) {
  __shared__ __align__(16) float lds[10240];  // 40KB: 4 waves x 2560 floats
  const int t = threadIdx.x;
  const int lane = t & 63;
  const int wave = t >> 6;
  const int wtid = blockIdx.x * 4 + wave;
  const int ot = wtid & otmask;
  const int nt = wtid >> otshift;

  float* wlds = &lds[wave * 2560];                      // B: 2 x 1024 floats
  unsigned int* alds = (unsigned int*)(wlds + 2048);    // A: 2 x 256 u32

  const float* wsrc = Wswz + (size_t)ot * KT * 1024 + lane * 4;
  const unsigned int* asrc = Aswz + (size_t)nt * KT * 256 + lane * 4;

  float acc[8][8];
#pragma unroll
  for (int j = 0; j < 8; j++)
#pragma unroll
    for (int i = 0; i < 8; i++) acc[j][i] = 0.f;

  // prologue: stage tile 0 (wave-private)
  dma16(wsrc, wlds);
  dma16(wsrc + 256, wlds + 256);
  dma16(wsrc + 512, wlds + 512);
  dma16(wsrc + 768, wlds + 768);
  dma16(asrc, alds);

  const int ny = (lane >> 3) * 8;  // rows ny..ny+7
  const int ox = (lane & 7) * 8;   // cols ox..ox+7

  for (int tile = 0; tile < KT; tile++) {
    const int cur = tile & 1, nxt = cur ^ 1;
    if (tile + 1 < KT) {  // wave-private prefetch, zero VGPR cost
      const float* wn = wsrc + (size_t)(tile + 1) * 1024;
      float* bl = wlds + nxt * 1024;
      dma16(wn, bl);
      dma16(wn + 256, bl + 256);
      dma16(wn + 512, bl + 512);
      dma16(wn + 768, bl + 768);
      dma16(asrc + (size_t)(tile + 1) * 256, alds + nxt * 256);
    }
    const float* Bc = wlds + cur * 1024;
    const unsigned int* Ac = alds + cur * 256;
#pragma unroll
    for (int kq = 0; kq < 4; kq++) {
      uint4 a0 = *(const uint4*)&Ac[kq * 64 + ny];      // rows ny..ny+3
      uint4 a1 = *(const uint4*)&Ac[kq * 64 + ny + 4];  // rows ny+4..ny+7
#pragma unroll
      for (int k2 = 0; k2 < 4; k2++) {
        const int kk = kq * 4 + k2;
        const int sh = k2 * 8;
        float av[8];
        av[0] = (float)((a0.x >> sh) & 0xffu);  // v_cvt_f32_ubyte
        av[1] = (float)((a0.y >> sh) & 0xffu);
        av[2] = (float)((a0.z >> sh) & 0xffu);
        av[3] = (float)((a0.w >> sh) & 0xffu);
        av[4] = (float)((a1.x >> sh) & 0xffu);
        av[5] = (float)((a1.y >> sh) & 0xffu);
        av[6] = (float)((a1.z >> sh) & 0xffu);
        av[7] = (float)((a1.w >> sh) & 0xffu);
        float4 b0 = *(const float4*)&Bc[kk * 64 + ox];
        float4 b1 = *(const float4*)&Bc[kk * 64 + ox + 4];
        float bv[8] = {b0.x, b0.y, b0.z, b0.w, b1.x, b1.y, b1.z, b1.w};
#pragma unroll
        for (int j = 0; j < 8; j++)
#pragma unroll
          for (int i = 0; i < 8; i++)
            acc[j][i] = fmaf(av[j], bv[i], acc[j][i]);
      }
    }
  }

  // store: rows nt*64+ny+j, cols ot*64+ox.. (guarded vs Ostore)
#pragma unroll
  for (int j = 0; j < 8; j++) {
    int n = nt * 64 + ny + j;
    int o0 = ot * 64 + ox;
    float* zp = Z + (size_t)n * Zld + o0;
    if (o0 + 7 < Ostore) {
      *(float4*)zp = make_float4(acc[j][0], acc[j][1], acc[j][2], acc[j][3]);
      *(float4*)(zp + 4) =
          make_float4(acc[j][4], acc[j][5], acc[j][6], acc[j][7]);
    } else {
#pragma unroll
      for (int q = 0; q < 8; q++)
        if (o0 + q < Ostore) zp[q] = acc[j][q];
    }
  }
}

// ---------------------------------------------------------------------------
// CUBA LIF recurrence: depth-4 x U=25 load pipeline. Exact per-step fp32
// mul/add chain. Mid layers write u8 spikes into the A image:
// byte = (n>>6)*16384 + koff + (n&63)*4, koff = (k>>4)*1024+((k>>2)&3)*256+(k&3)
// ---------------------------------------------------------------------------
template <bool FINAL>
__global__ __launch_bounds__(64) void cuba_kernel(
    const float* __restrict__ Z, uint8_t* __restrict__ Sout,
    float* __restrict__ Fout, unsigned int* __restrict__ cnt, int O,
    int total) {
  int gid = blockIdx.x * 64 + threadIdx.x;
  unsigned int c = 0;
  if (gid < total) {
    int b = gid / O;
    int o = gid - b * O;
    const int nb = b * TT;
    const float* zp = Z + (size_t)nb * O + o;
    float* fp = Fout + ((size_t)b * O + o) * TT;
    const int koff = (o >> 4) * 1024 + ((o >> 2) & 3) * 256 + (o & 3);
    float cur = 0.f, volt = 0.f;
    constexpr int U = 25;
    float z0[U], z1[U], z2[U], z3[U];

#define LOADB(buf, tbase)                         \
  _Pragma("unroll") for (int u = 0; u < U; u++) { \
    buf[u] = zp[(size_t)((tbase) + u) * O];       \
  }
#define COMPB(buf, tbase)                                              \
  _Pragma("unroll") for (int u = 0; u < U; u++) {                      \
    cur = __fadd_rn(__fmul_rn(0.75f, cur), buf[u]);                    \
    volt = __fadd_rn(__fmul_rn(0.97f, volt), cur);                     \
    bool fire = volt >= 1.25f;                                         \
    volt = fire ? 0.f : volt;                                          \
    c += fire ? 1u : 0u;                                               \
    if (FINAL) {                                                       \
      fp[(tbase) + u] = fire ? 1.f : 0.f;                              \
    } else {                                                           \
      int n = nb + (tbase) + u;                                        \
      Sout[(size_t)(n >> 6) * 16384 + koff + ((n & 63) << 2)] =        \
          (uint8_t)(fire ? 1 : 0);                                     \
    }                                                                  \
  }

    LOADB(z0, 0)
    LOADB(z1, U)
    LOADB(z2, 2 * U)
    for (int i = 0; i < 10; i++) {
      const int base = i * 4 * U;
      LOADB(z3, base + 3 * U)
      COMPB(z0, base)
      if (i < 9) LOADB(z0, base + 4 * U)
      COMPB(z1, base + U)
      if (i < 9) LOADB(z1, base + 5 * U)
      COMPB(z2, base + 2 * U)
      if (i < 9) LOADB(z2, base + 6 * U)
      COMPB(z3, base + 3 * U)
    }
#undef LOADB
#undef COMPB
  }
#pragma unroll
  for (int off = 32; off; off >>= 1) c += __shfl_down(c, off, 64);
  if ((threadIdx.x & 63) == 0) atomicAdd(cnt, c);
}

// ---------------------------------------------------------------------------
// Fused prep: cnt zero + input image (KT=2) + 4 weight swizzles.
// ---------------------------------------------------------------------------
__device__ __forceinline__ void prep_w_item(const float* __restrict__ W,
                                            float* __restrict__ Wsw, int O,
                                            int K, int KT, int i) {
  int o6 = i & 63;
  int k16 = (i >> 6) & 15;
  int blkid = i >> 10;
  int kt = blkid & (KT - 1);
  int ot = blkid / KT;
  int k = kt * 16 + k16;
  int o = ot * 64 + o6;
  Wsw[i] = (k < K && o < O) ? W[(size_t)o * K + k] : 0.f;
}

__global__ __launch_bounds__(256) void prep_all(
    const float* __restrict__ X, const float* __restrict__ W1,
    const float* __restrict__ W2, const float* __restrict__ W3,
    const float* __restrict__ W4, unsigned int* __restrict__ Ain,
    float* __restrict__ Ws1, float* __restrict__ Ws2,
    float* __restrict__ Ws3, float* __restrict__ Ws4,
    unsigned int* __restrict__ cnt) {
  const int blk = blockIdx.x;
  const int tid = threadIdx.x;
  if (blk == 0 && tid < 8) cnt[tid] = 0u;
  if (blk < 250) {
    int gid = blk * 256 + tid;  // n
    unsigned int w[8];
#pragma unroll
    for (int i = 0; i < 8; i++) w[i] = 0u;
#pragma unroll
    for (int c = 0; c < 20; c++) {
      float v = X[((size_t)(gid / TT) * 20 + c) * TT + (gid % TT)];
      w[c >> 2] |= (v != 0.f ? 1u : 0u) << ((c & 3) * 8);
    }
    // A image, KT=2: idx = (n>>6)*512 + kt*256 + kd*64 + (n&63)
    unsigned int base = (gid >> 6) * 512 + (gid & 63);
#pragma unroll
    for (int kd8 = 0; kd8 < 8; kd8++)
      Ain[base + (kd8 >> 2) * 256 + (kd8 & 3) * 64] = w[kd8];
  } else if (blk < 282) {
    prep_w_item(W1, Ws1, 256, 20, 2, (blk - 250) * 256 + tid);  // 8192
  } else if (blk < 538) {
    prep_w_item(W2, Ws2, 256, 256, 16, (blk - 282) * 256 + tid);  // 65536
  } else if (blk < 794) {
    prep_w_item(W3, Ws3, 256, 256, 16, (blk - 538) * 256 + tid);  // 65536
  } else {
    prep_w_item(W4, Ws4, 35, 256, 16, (blk - 794) * 256 + tid);  // 16384
  }
}

__global__ void finalize_counts(const unsigned int* __restrict__ cnt,
                                float* __restrict__ out) {
  int i = threadIdx.x;
  if (i < 4) {
    const float denom[4] = {16384000.f, 16384000.f, 16384000.f, 2240000.f};
    out[i] = (float)cnt[i] / denom[i];
  }
}

// ---------------------------------------------------------------------------
extern "C" void kernel_launch(void* const* d_in, const int* in_sizes, int n_in,
                              void* d_out, int out_size, void* d_ws,
                              size_t ws_size, hipStream_t stream) {
  const float* X = (const float*)d_in[0];
  const float* W1 = (const float*)d_in[1];
  const float* W2 = (const float*)d_in[2];
  const float* W3 = (const float*)d_in[3];
  const float* W4 = (const float*)d_in[4];
  float* out = (float*)d_out;

  char* ws = (char*)d_ws;
  unsigned int* cnt = (unsigned int*)ws;                       // 256 B
  float* Z = (float*)(ws + 256);                               // 65,536,000
  unsigned int* Sa = (unsigned int*)(ws + 256 + 65536000ull);  // 16,384,000
  unsigned int* Sb = Sa + 4096000ull;                          // 16,384,000
  unsigned int* Sin = Sb + 4096000ull;                         // 2,048,000
  float* Ws1 = (float*)(Sin + 512000ull);                      // 8192 f
  float* Ws2 = Ws1 + 8192;                                     // 65536 f
  float* Ws3 = Ws2 + 65536;                                    // 65536 f
  float* Ws4 = Ws3 + 65536;                                    // 16384 f

  prep_all<<<858, 256, 0, stream>>>(X, W1, W2, W3, W4, Sin, Ws1, Ws2, Ws3,
                                    Ws4, cnt);

  // big layers: 1000 n-tiles x 4 o-tiles / 4 waves = 1000 blocks
  gemm_wp<<<1000, 256, 0, stream>>>(Sin, Ws1, Z, 2, 3, 2, 256, 256);
  cuba_kernel<false><<<256, 64, 0, stream>>>(Z, (uint8_t*)Sa, nullptr, cnt + 0,
                                             256, 16384);
  gemm_wp<<<1000, 256, 0, stream>>>(Sa, Ws2, Z, 16, 3, 2, 256, 256);
  cuba_kernel<false><<<256, 64, 0, stream>>>(Z, (uint8_t*)Sb, nullptr, cnt + 1,
                                             256, 16384);
  gemm_wp<<<1000, 256, 0, stream>>>(Sb, Ws3, Z, 16, 3, 2, 256, 256);
  cuba_kernel<false><<<256, 64, 0, stream>>>(Z, (uint8_t*)Sa, nullptr, cnt + 2,
                                             256, 16384);
  // layer 4: 1000 n-tiles x 1 o-tile / 4 waves = 250 blocks
  gemm_wp<<<250, 256, 0, stream>>>(Sa, Ws4, Z, 16, 0, 0, 35, 35);
  cuba_kernel<true><<<35, 64, 0, stream>>>(Z, nullptr, out, cnt + 3, 35, 2240);
  finalize_counts<<<1, 64, 0, stream>>>(cnt, out + 2240000);
}